// Round 1
// baseline (449.555 us; speedup 1.0000x reference)
//
#include <hip/hip_runtime.h>

// Problem constants (fixed by the reference harness).
#define IMG 224
#define PSZ 4
#define NPX (IMG / PSZ)            // 56
#define NPATCH (NPX * NPX)         // 3136
#define BB 32
#define RR 16
#define DD 768
#define NCHUNK 16
#define CHUNK (NPATCH / NCHUNK)    // 196 (divisible by 4 for the unroll)
#define T2 192                     // pooling threads: 192 * float4 = 768 = D

// ---------------------------------------------------------------------------
// K1: per-patch dominant segment id (mode of 16 labels, ties -> smallest id),
// plus per-(b,r) patch counts via atomics (512 bins, ~196 adds each).
// Histogram packed into two u64 (8 bits per bin; max count 16 fits).
// ---------------------------------------------------------------------------
__global__ __launch_bounds__(256) void k_segids(const int* __restrict__ seg,
                                                int* __restrict__ seg_ids,
                                                int* __restrict__ counts) {
    int t = blockIdx.x * 256 + threadIdx.x;
    if (t >= BB * NPATCH) return;
    int b = t / NPATCH;
    int n = t - b * NPATCH;
    int py = n / NPX, px = n - py * NPX;
    const int* base = seg + ((size_t)b * IMG + (size_t)py * PSZ) * IMG + px * PSZ;
    unsigned long long lo = 0ull, hi = 0ull;
#pragma unroll
    for (int i = 0; i < PSZ; i++) {
        int4 v = *(const int4*)(base + (size_t)i * IMG);  // 16B aligned: row stride 896B, col off 16B
        int ss[4] = {v.x, v.y, v.z, v.w};
#pragma unroll
        for (int j = 0; j < 4; j++) {
            int s = ss[j];
            unsigned long long inc = 1ull << ((s & 7) * 8);
            if (s < 8) lo += inc; else hi += inc;
        }
    }
    int best = 0, bc = -1;
#pragma unroll
    for (int r = 0; r < RR; r++) {
        unsigned long long word = (r < 8) ? lo : hi;
        int c = (int)((word >> ((r & 7) * 8)) & 0xffull);
        if (c > bc) { bc = c; best = r; }   // strict >: ties break to smallest r (matches argmax)
    }
    seg_ids[t] = best;
    atomicAdd(&counts[b * RR + best], 1);
}

// ---------------------------------------------------------------------------
// K2: streaming accumulation. Block = (b, patch-chunk). Thread t owns d in
// [4t, 4t+4). 16 float4 register accumulators, predicated FMA (seg is
// wave-uniform per patch -> no divergence). ATOMIC=false writes partials
// [chunk][B][R][D]; ATOMIC=true adds straight into d_out (ws fallback).
// ---------------------------------------------------------------------------
template <bool ATOMIC>
__global__ __launch_bounds__(T2) void k_pool(const float* __restrict__ emb,
                                             const int* __restrict__ seg_ids,
                                             float* __restrict__ dst) {
    const int blk = blockIdx.x;
    const int b = blk / NCHUNK;
    const int c = blk - b * NCHUNK;
    const int n0 = c * CHUNK;
    __shared__ int sseg[CHUNK];
    for (int i = threadIdx.x; i < CHUNK; i += T2)
        sseg[i] = seg_ids[b * NPATCH + n0 + i];
    __syncthreads();

    const int t = threadIdx.x;
    const float* src = emb + ((size_t)(b * NPATCH + n0)) * DD + t * 4;

    float4 acc[RR];
#pragma unroll
    for (int r = 0; r < RR; r++) acc[r] = make_float4(0.f, 0.f, 0.f, 0.f);

    for (int p = 0; p < CHUNK; p += 4) {
        float4 v0 = *(const float4*)(src + (size_t)(p + 0) * DD);
        float4 v1 = *(const float4*)(src + (size_t)(p + 1) * DD);
        float4 v2 = *(const float4*)(src + (size_t)(p + 2) * DD);
        float4 v3 = *(const float4*)(src + (size_t)(p + 3) * DD);
        int s0 = sseg[p + 0], s1 = sseg[p + 1], s2 = sseg[p + 2], s3 = sseg[p + 3];
#pragma unroll
        for (int r = 0; r < RR; r++) {
            float w0 = (s0 == r) ? 1.f : 0.f;
            float w1 = (s1 == r) ? 1.f : 0.f;
            float w2 = (s2 == r) ? 1.f : 0.f;
            float w3 = (s3 == r) ? 1.f : 0.f;
            acc[r].x = fmaf(w0, v0.x, acc[r].x);
            acc[r].y = fmaf(w0, v0.y, acc[r].y);
            acc[r].z = fmaf(w0, v0.z, acc[r].z);
            acc[r].w = fmaf(w0, v0.w, acc[r].w);
            acc[r].x = fmaf(w1, v1.x, acc[r].x);
            acc[r].y = fmaf(w1, v1.y, acc[r].y);
            acc[r].z = fmaf(w1, v1.z, acc[r].z);
            acc[r].w = fmaf(w1, v1.w, acc[r].w);
            acc[r].x = fmaf(w2, v2.x, acc[r].x);
            acc[r].y = fmaf(w2, v2.y, acc[r].y);
            acc[r].z = fmaf(w2, v2.z, acc[r].z);
            acc[r].w = fmaf(w2, v2.w, acc[r].w);
            acc[r].x = fmaf(w3, v3.x, acc[r].x);
            acc[r].y = fmaf(w3, v3.y, acc[r].y);
            acc[r].z = fmaf(w3, v3.z, acc[r].z);
            acc[r].w = fmaf(w3, v3.w, acc[r].w);
        }
    }

    if (ATOMIC) {
        float* o = dst + ((size_t)b * RR) * DD + t * 4;
#pragma unroll
        for (int r = 0; r < RR; r++) {
            atomicAdd(o + r * DD + 0, acc[r].x);
            atomicAdd(o + r * DD + 1, acc[r].y);
            atomicAdd(o + r * DD + 2, acc[r].z);
            atomicAdd(o + r * DD + 3, acc[r].w);
        }
    } else {
        float* o = dst + (((size_t)c * BB + b) * RR) * DD + t * 4;
#pragma unroll
        for (int r = 0; r < RR; r++)
            *(float4*)(o + r * DD) = acc[r];
    }
}

// ---------------------------------------------------------------------------
// K3: reduce NCHUNK partials (mostly L3-warm) and divide by max(count, 1).
// ---------------------------------------------------------------------------
__global__ __launch_bounds__(256) void k_finish_part(const float* __restrict__ part,
                                                     const int* __restrict__ counts,
                                                     float* __restrict__ out) {
    int e = blockIdx.x * 256 + threadIdx.x;
    if (e >= BB * RR * DD) return;
    float s = 0.f;
#pragma unroll
    for (int c = 0; c < NCHUNK; c++) s += part[(size_t)c * (BB * RR * DD) + e];
    int br = e / DD;
    float cnt = (float)counts[br];
    out[e] = s / fmaxf(cnt, 1.f);
}

__global__ __launch_bounds__(256) void k_finish_atomic(const int* __restrict__ counts,
                                                       float* __restrict__ out) {
    int e = blockIdx.x * 256 + threadIdx.x;
    if (e >= BB * RR * DD) return;
    int br = e / DD;
    float cnt = (float)counts[br];
    out[e] = out[e] / fmaxf(cnt, 1.f);
}

// ---------------------------------------------------------------------------
// Workspace layout:
//   [0, 401408)            seg_ids  int[B*NPATCH]
//   [401408, 403456)       counts   int[B*R]          (memset 0 each launch)
//   [403456, 25569280)     partials float[NCHUNK][B][R][D]  (fully overwritten)
// ---------------------------------------------------------------------------
extern "C" void kernel_launch(void* const* d_in, const int* in_sizes, int n_in,
                              void* d_out, int out_size, void* d_ws, size_t ws_size,
                              hipStream_t stream) {
    const float* emb = (const float*)d_in[0];
    const int* segmap = (const int*)d_in[1];
    (void)in_sizes; (void)n_in; (void)out_size;

    char* ws = (char*)d_ws;
    int* seg_ids = (int*)ws;
    int* counts = (int*)(ws + 401408);
    float* part = (float*)(ws + 403456);
    const size_t need = 403456 + (size_t)NCHUNK * BB * RR * DD * sizeof(float);
    float* out = (float*)d_out;

    hipMemsetAsync(counts, 0, BB * RR * sizeof(int), stream);
    k_segids<<<(BB * NPATCH + 255) / 256, 256, 0, stream>>>(segmap, seg_ids, counts);

    if (ws_size >= need) {
        k_pool<false><<<BB * NCHUNK, T2, 0, stream>>>(emb, seg_ids, part);
        k_finish_part<<<(BB * RR * DD + 255) / 256, 256, 0, stream>>>(part, counts, out);
    } else {
        // Fallback: atomics straight into d_out (needs only ~0.4 MB of ws).
        hipMemsetAsync(out, 0, (size_t)BB * RR * DD * sizeof(float), stream);
        k_pool<true><<<BB * NCHUNK, T2, 0, stream>>>(emb, seg_ids, out);
        k_finish_atomic<<<(BB * RR * DD + 255) / 256, 256, 0, stream>>>(counts, out);
    }
}

// Round 2
// 437.887 us; speedup vs baseline: 1.0266x; 1.0266x over previous
//
#include <hip/hip_runtime.h>

// Problem constants (fixed by the reference harness).
#define IMG 224
#define PSZ 4
#define NPX (IMG / PSZ)            // 56
#define NPATCH (NPX * NPX)         // 3136
#define BB 32
#define RR 16
#define DD 768
#define NCHUNK 32
#define CHUNK (NPATCH / NCHUNK)    // 98
#define T2 192                     // pooling threads: 192 * float4 = 768 = D

// ---------------------------------------------------------------------------
// K1 (fused): block = (b, patch-chunk).
// Phase A: each block computes the dominant segment id (mode, ties -> smallest
//          label, matching jnp.argmax over sorted bins) for its 98 patches,
//          plus a block-local histogram -> 16 global atomics into counts.
// Phase B: streaming accumulation. Thread t owns d in [4t, 4t+4).
//          16 float4 register accumulators, predicated FMA (seg id is
//          wave-uniform per patch -> no divergence).
// ATOMIC=false writes partials [chunk][B][R][D]; ATOMIC=true adds into d_out.
// ---------------------------------------------------------------------------
template <bool ATOMIC>
__global__ __launch_bounds__(T2) void k_pool(const float* __restrict__ emb,
                                             const int* __restrict__ segmap,
                                             int* __restrict__ counts,
                                             float* __restrict__ dst) {
    const int blk = blockIdx.x;
    const int b = blk / NCHUNK;
    const int c = blk - b * NCHUNK;
    const int n0 = c * CHUNK;

    __shared__ int sseg[CHUNK];
    __shared__ int lcnt[RR];
    if (threadIdx.x < RR) lcnt[threadIdx.x] = 0;
    __syncthreads();

    // ---- Phase A: per-patch mode of 16 labels (8-bit-packed u64 histogram) --
    for (int i = threadIdx.x; i < CHUNK; i += T2) {
        int n = n0 + i;
        int py = n / NPX, px = n - py * NPX;
        const int* base = segmap + ((size_t)b * IMG + (size_t)py * PSZ) * IMG + px * PSZ;
        unsigned long long lo = 0ull, hi = 0ull;
#pragma unroll
        for (int j = 0; j < PSZ; j++) {
            int4 v = *(const int4*)(base + (size_t)j * IMG);  // 16B-aligned
            int ss[4] = {v.x, v.y, v.z, v.w};
#pragma unroll
            for (int k = 0; k < 4; k++) {
                int s = ss[k];
                unsigned long long inc = 1ull << ((s & 7) * 8);
                if (s < 8) lo += inc; else hi += inc;
            }
        }
        int best = 0, bc = -1;
#pragma unroll
        for (int r = 0; r < RR; r++) {
            unsigned long long word = (r < 8) ? lo : hi;
            int cc = (int)((word >> ((r & 7) * 8)) & 0xffull);
            if (cc > bc) { bc = cc; best = r; }  // strict >: tie -> smallest r
        }
        sseg[i] = best;
        atomicAdd(&lcnt[best], 1);
    }
    __syncthreads();
    if (threadIdx.x < RR)
        atomicAdd(&counts[b * RR + threadIdx.x], lcnt[threadIdx.x]);

    // ---- Phase B: stream 98 patches x 768 floats, accumulate per segment ----
    const int t = threadIdx.x;
    const float* src = emb + ((size_t)(b * NPATCH + n0)) * DD + t * 4;

    float4 acc[RR];
#pragma unroll
    for (int r = 0; r < RR; r++) acc[r] = make_float4(0.f, 0.f, 0.f, 0.f);

#pragma unroll 1
    for (int p = 0; p < CHUNK - 2; p += 4) {
        float4 v0 = *(const float4*)(src + (size_t)(p + 0) * DD);
        float4 v1 = *(const float4*)(src + (size_t)(p + 1) * DD);
        float4 v2 = *(const float4*)(src + (size_t)(p + 2) * DD);
        float4 v3 = *(const float4*)(src + (size_t)(p + 3) * DD);
        int s0 = sseg[p + 0], s1 = sseg[p + 1], s2 = sseg[p + 2], s3 = sseg[p + 3];
#pragma unroll
        for (int r = 0; r < RR; r++) {
            float w0 = (s0 == r) ? 1.f : 0.f;
            float w1 = (s1 == r) ? 1.f : 0.f;
            float w2 = (s2 == r) ? 1.f : 0.f;
            float w3 = (s3 == r) ? 1.f : 0.f;
            acc[r].x = fmaf(w0, v0.x, acc[r].x);
            acc[r].y = fmaf(w0, v0.y, acc[r].y);
            acc[r].z = fmaf(w0, v0.z, acc[r].z);
            acc[r].w = fmaf(w0, v0.w, acc[r].w);
            acc[r].x = fmaf(w1, v1.x, acc[r].x);
            acc[r].y = fmaf(w1, v1.y, acc[r].y);
            acc[r].z = fmaf(w1, v1.z, acc[r].z);
            acc[r].w = fmaf(w1, v1.w, acc[r].w);
            acc[r].x = fmaf(w2, v2.x, acc[r].x);
            acc[r].y = fmaf(w2, v2.y, acc[r].y);
            acc[r].z = fmaf(w2, v2.z, acc[r].z);
            acc[r].w = fmaf(w2, v2.w, acc[r].w);
            acc[r].x = fmaf(w3, v3.x, acc[r].x);
            acc[r].y = fmaf(w3, v3.y, acc[r].y);
            acc[r].z = fmaf(w3, v3.z, acc[r].z);
            acc[r].w = fmaf(w3, v3.w, acc[r].w);
        }
    }
    {   // compile-time tail: CHUNK = 98 = 24*4 + 2
        const int p = CHUNK - 2;
        float4 v0 = *(const float4*)(src + (size_t)(p + 0) * DD);
        float4 v1 = *(const float4*)(src + (size_t)(p + 1) * DD);
        int s0 = sseg[p + 0], s1 = sseg[p + 1];
#pragma unroll
        for (int r = 0; r < RR; r++) {
            float w0 = (s0 == r) ? 1.f : 0.f;
            float w1 = (s1 == r) ? 1.f : 0.f;
            acc[r].x = fmaf(w0, v0.x, acc[r].x);
            acc[r].y = fmaf(w0, v0.y, acc[r].y);
            acc[r].z = fmaf(w0, v0.z, acc[r].z);
            acc[r].w = fmaf(w0, v0.w, acc[r].w);
            acc[r].x = fmaf(w1, v1.x, acc[r].x);
            acc[r].y = fmaf(w1, v1.y, acc[r].y);
            acc[r].z = fmaf(w1, v1.z, acc[r].z);
            acc[r].w = fmaf(w1, v1.w, acc[r].w);
        }
    }

    if (ATOMIC) {
        float* o = dst + ((size_t)b * RR) * DD + t * 4;
#pragma unroll
        for (int r = 0; r < RR; r++) {
            atomicAdd(o + r * DD + 0, acc[r].x);
            atomicAdd(o + r * DD + 1, acc[r].y);
            atomicAdd(o + r * DD + 2, acc[r].z);
            atomicAdd(o + r * DD + 3, acc[r].w);
        }
    } else {
        float* o = dst + (((size_t)c * BB + b) * RR) * DD + t * 4;
#pragma unroll
        for (int r = 0; r < RR; r++)
            *(float4*)(o + r * DD) = acc[r];
    }
}

// ---------------------------------------------------------------------------
// K2: block per (b,r). Reduce NCHUNK partial rows (L3-warm, coalesced float4),
// divide by max(count,1) (empty superpixels stay zero, matching reference).
// ---------------------------------------------------------------------------
__global__ __launch_bounds__(T2) void k_finish_part(const float* __restrict__ part,
                                                    const int* __restrict__ counts,
                                                    float* __restrict__ out) {
    const int br = blockIdx.x;            // b*RR + r
    const int t = threadIdx.x;
    const float* p0 = part + (size_t)br * DD + t * 4;
    float4 s = make_float4(0.f, 0.f, 0.f, 0.f);
#pragma unroll
    for (int c = 0; c < NCHUNK; c++) {
        float4 v = *(const float4*)(p0 + (size_t)c * (BB * RR * DD));
        s.x += v.x; s.y += v.y; s.z += v.z; s.w += v.w;
    }
    float inv = 1.f / fmaxf((float)counts[br], 1.f);
    float4 o = make_float4(s.x * inv, s.y * inv, s.z * inv, s.w * inv);
    *(float4*)(out + (size_t)br * DD + t * 4) = o;
}

__global__ __launch_bounds__(256) void k_finish_atomic(const int* __restrict__ counts,
                                                       float* __restrict__ out) {
    int e = blockIdx.x * 256 + threadIdx.x;
    if (e >= BB * RR * DD) return;
    float cnt = (float)counts[e / DD];
    out[e] = out[e] / fmaxf(cnt, 1.f);
}

// ---------------------------------------------------------------------------
// Workspace layout:
//   [0, 2048)            counts   int[B*R]                   (memset 0)
//   [2048, 50333696)     partials float[NCHUNK][B][R][D]     (fully overwritten)
// ---------------------------------------------------------------------------
extern "C" void kernel_launch(void* const* d_in, const int* in_sizes, int n_in,
                              void* d_out, int out_size, void* d_ws, size_t ws_size,
                              hipStream_t stream) {
    const float* emb = (const float*)d_in[0];
    const int* segmap = (const int*)d_in[1];
    (void)in_sizes; (void)n_in; (void)out_size;

    char* ws = (char*)d_ws;
    int* counts = (int*)ws;
    float* part = (float*)(ws + 2048);
    const size_t need = 2048 + (size_t)NCHUNK * BB * RR * DD * sizeof(float);
    float* out = (float*)d_out;

    hipMemsetAsync(counts, 0, BB * RR * sizeof(int), stream);

    if (ws_size >= need) {
        k_pool<false><<<BB * NCHUNK, T2, 0, stream>>>(emb, segmap, counts, part);
        k_finish_part<<<BB * RR, T2, 0, stream>>>(part, counts, out);
    } else {
        // Fallback: atomics straight into d_out (needs only 2 KB of ws).
        hipMemsetAsync(out, 0, (size_t)BB * RR * DD * sizeof(float), stream);
        k_pool<true><<<BB * NCHUNK, T2, 0, stream>>>(emb, segmap, counts, out);
        k_finish_atomic<<<(BB * RR * DD + 255) / 256, 256, 0, stream>>>(counts, out);
    }
}